// Round 9
// baseline (161.356 us; speedup 1.0000x reference)
//
#include <hip/hip_runtime.h>
#include <cstdint>
#include <cstddef>
#include <math.h>

typedef _Float16 f16;
typedef _Float16 f16x8 __attribute__((ext_vector_type(8)));
typedef _Float16 f16x4 __attribute__((ext_vector_type(4)));
typedef float f32x4 __attribute__((ext_vector_type(4)));
typedef float f32x16 __attribute__((ext_vector_type(16)));

#define MFMA16(A, B, C) __builtin_amdgcn_mfma_f32_16x16x32_f16((A), (B), (C), 0, 0, 0)
#define MFMA32(A, B, C) __builtin_amdgcn_mfma_f32_32x32x16_f16((A), (B), (C), 0, 0, 0)

#if __has_builtin(__builtin_amdgcn_exp2f)
#define EXP2(x) __builtin_amdgcn_exp2f(x)
#else
#define EXP2(x) exp2f(x)
#endif

__device__ __forceinline__ f16x8 ld8(const f16* p) { return *(const f16x8*)p; }
__device__ __forceinline__ void st8(f16* p, f16x8 v) { *(f16x8*)p = v; }
__device__ __forceinline__ void st4(f16* p, f16x4 v) { *(f16x4*)p = v; }

__device__ __forceinline__ void gll16(const f16* g, f16* l) {
    __builtin_amdgcn_global_load_lds(
        (__attribute__((address_space(1))) void*)(uintptr_t)g,
        (__attribute__((address_space(3))) void*)(unsigned)(uintptr_t)l,
        16, 0, 0);
}

// ---------------- K0: fp32 -> f16 cast of Q,K,V,Wq,Wk,Wv,Wo ----------------
// ws f16 layout (elements):
//   Qc 0, Kc 2097152, Vc 4194304, Wqc 6291456, Wkc 7340032, Wvc 8388608,
//   Woc 9437184, qlin 10485760, klin 12582912, vT 14680064, merged 16777216
__global__ __launch_bounds__(256) void cast_all(
    const float* __restrict__ Q, const float* __restrict__ K, const float* __restrict__ V,
    const float* __restrict__ Wq, const float* __restrict__ Wk, const float* __restrict__ Wv,
    const float* __restrict__ Wo, f16* __restrict__ dst)
{
    size_t e = ((size_t)blockIdx.x * 256 + threadIdx.x) * 8;
    const float* s; size_t r;
    if (e < 2097152)      { s = Q;  r = e; }
    else if (e < 4194304) { s = K;  r = e - 2097152; }
    else if (e < 6291456) { s = V;  r = e - 4194304; }
    else if (e < 7340032) { s = Wq; r = e - 6291456; }
    else if (e < 8388608) { s = Wk; r = e - 7340032; }
    else if (e < 9437184) { s = Wv; r = e - 8388608; }
    else                  { s = Wo; r = e - 9437184; }
    float4 a = *(const float4*)(s + r);
    float4 b = *(const float4*)(s + r + 4);
    f16x8 o;
    o[0]=(f16)a.x; o[1]=(f16)a.y; o[2]=(f16)a.z; o[3]=(f16)a.w;
    o[4]=(f16)b.x; o[5]=(f16)b.y; o[6]=(f16)b.z; o[7]=(f16)b.w;
    st8(dst + e, o);
}

// ---------------- K1: fused QKV GEMM, 128x128 tile, BK=64, dbuf, MFMA32 -----
// grid (24,16): bx = mat*8 + bn(128 n-cols), by = bm(128 m-rows). 4 waves in
// 2x2, each computing 64x64 via 4 MFMA32 per k-step (2 A-frags + 2 B-frags ->
// reads/MFMA = 1.0; staging bytes per FLOP halved vs 64x128).
// mat 0 -> qlin pre-scaled by log2e/32; mat 1 -> klin; mat 2 -> vT transposed.
__global__ __launch_bounds__(256, 2) void qkv_gemm(
    const f16* __restrict__ ws, const float* __restrict__ bq,
    const float* __restrict__ bk, const float* __restrict__ bv,
    f16* __restrict__ outbase)
{
    const int bx = blockIdx.x, bm = blockIdx.y;
    const int mat = bx >> 3, bn = bx & 7;
    const f16* A  = ws + (size_t)mat * 2097152;
    const f16* Bw = ws + 6291456 + (size_t)mat * 1048576;
    const float* bias = (mat == 0) ? bq : (mat == 1) ? bk : bv;
    f16* C = outbase + (size_t)mat * 2097152;

    __shared__ f16 As[2][8192];   // [buf][128 rows][64 cols], 16B chunks swizzled
    __shared__ f16 Bs[2][8192];
    const int t = threadIdx.x;
    const int w = t >> 6, lane = t & 63, l5 = lane & 31, hh = lane >> 5;
    const int wr = w >> 1, wc = w & 1;                // 2x2 wave grid
    const int swz = ((lane & 7) ^ (lane >> 3)) * 8;   // swizzled source col
    const int l7 = l5 & 7;

    // staging: wave w stages rows w*32 .. w*32+31 of both tiles (4 gll16 each)
    const f16* Ap = A  + (size_t)(bm * 128 + w * 32 + (lane >> 3)) * 1024 + swz;
    const f16* Bp = Bw + (size_t)(bn * 128 + w * 32 + (lane >> 3)) * 1024 + swz;

    f32x16 acc[2][2] = {};

    #pragma unroll
    for (int q = 0; q < 4; ++q) {
        gll16(Ap + q * 8192, &As[0][(w * 32 + q * 8) * 64]);
        gll16(Bp + q * 8192, &Bs[0][(w * 32 + q * 8) * 64]);
    }

    for (int kt = 0; kt < 16; ++kt) {
        const int cur = kt & 1;
        __syncthreads();
        if (kt < 15) {
            const f16* Ak = Ap + (kt + 1) * 64;
            const f16* Bk = Bp + (kt + 1) * 64;
            #pragma unroll
            for (int q = 0; q < 4; ++q) {
                gll16(Ak + q * 8192, &As[cur ^ 1][(w * 32 + q * 8) * 64]);
                gll16(Bk + q * 8192, &Bs[cur ^ 1][(w * 32 + q * 8) * 64]);
            }
        }
        const f16* Ac = As[cur];
        const f16* Bc = Bs[cur];
        #pragma unroll
        for (int ks = 0; ks < 4; ++ks) {
            const int c = ((ks * 2 + hh) ^ l7) * 8;   // 16B chunk, swizzle-corrected
            f16x8 af0 = ld8(&Ac[(wr * 64      + l5) * 64 + c]);
            f16x8 af1 = ld8(&Ac[(wr * 64 + 32 + l5) * 64 + c]);
            f16x8 bf0 = ld8(&Bc[(wc * 64      + l5) * 64 + c]);
            f16x8 bf1 = ld8(&Bc[(wc * 64 + 32 + l5) * 64 + c]);
            acc[0][0] = MFMA32(af0, bf0, acc[0][0]);
            acc[0][1] = MFMA32(af0, bf1, acc[0][1]);
            acc[1][0] = MFMA32(af1, bf0, acc[1][0]);
            acc[1][1] = MFMA32(af1, bf1, acc[1][1]);
        }
    }

    const float qscale = 0.04508422002778009f;   // log2(e)/32 folded into qlin
    #pragma unroll
    for (int j = 0; j < 2; ++j) {
        const int n = bn * 128 + wc * 64 + j * 32 + l5;   // lane owns one col per j
        const float bv_ = bias[n];
        if (mat == 0) {
            #pragma unroll
            for (int i = 0; i < 2; ++i)
                #pragma unroll
                for (int r = 0; r < 16; ++r) {
                    const int m = bm * 128 + wr * 64 + i * 32 + (r & 3) + 8 * (r >> 2) + 4 * hh;
                    C[(size_t)m * 1024 + n] = (f16)((acc[i][j][r] + bv_) * qscale);
                }
        } else if (mat == 1) {
            #pragma unroll
            for (int i = 0; i < 2; ++i)
                #pragma unroll
                for (int r = 0; r < 16; ++r) {
                    const int m = bm * 128 + wr * 64 + i * 32 + (r & 3) + 8 * (r >> 2) + 4 * hh;
                    C[(size_t)m * 1024 + n] = (f16)(acc[i][j][r] + bv_);
                }
        } else {
            // vT[((bb*64 + h)*16 + e)*1024 + s], h = n>>4, e = n&15
            const int hN = n >> 4, eN = n & 15;
            #pragma unroll
            for (int i = 0; i < 2; ++i)
                #pragma unroll
                for (int g = 0; g < 4; ++g) {
                    const int m0 = bm * 128 + wr * 64 + i * 32 + 8 * g + 4 * hh;
                    const int bb = m0 >> 10, s0 = m0 & 1023;
                    f16x4 pv;
                    pv[0] = (f16)(acc[i][j][4 * g + 0] + bv_);
                    pv[1] = (f16)(acc[i][j][4 * g + 1] + bv_);
                    pv[2] = (f16)(acc[i][j][4 * g + 2] + bv_);
                    pv[3] = (f16)(acc[i][j][4 * g + 3] + bv_);
                    st4(C + ((size_t)((bb * 64 + hN) * 16 + eN)) * 1024 + s0, pv);
                }
        }
    }
}

// ---------------- K2: flash attention, 64 heads of dim 16 (unchanged) -------
__global__ __launch_bounds__(256, 4) void attn(
    const f16* __restrict__ qlin, const f16* __restrict__ klin,
    const f16* __restrict__ vT, f16* __restrict__ merged)
{
    __shared__ f16 Ks[2][2048];      // [buf][key 128][e 16], swizzled chunks
    __shared__ f16 Vs[2][2176];      // [buf][e 16][key 128], pitch 136
    __shared__ f16 Ps[4][1280];      // per-wave P [q 32][key 32], pitch 40

    const int t = threadIdx.x;
    const int w = t >> 6, lane = t & 63;
    const int l5 = lane & 31, hh = lane >> 5, lg = (lane >> 4) & 3, ll = lane & 15;
    const int h = blockIdx.x, qt = blockIdx.y, b = blockIdx.z;

    const int rowQ0 = b * 1024 + qt * 128;
    const int colh = h * 16;

    f16x8 qf = ld8(qlin + (size_t)(rowQ0 + w * 32 + l5) * 1024 + colh + hh * 8);

    const int sp = ((lane & 7) - (lane >> 3)) & 7;
    const f16* kptr = klin + (size_t)(b * 1024 + w * 32 + (lane >> 3) * 4 + (sp >> 1)) * 1024
                      + colh + (sp & 1) * 8;
    const int ve = t >> 4, vk = (t & 15) * 8;
    const f16* vptr = vT + (size_t)((b * 64 + h) * 16 + ve) * 1024 + vk;
    f16* vdst0 = &Vs[0][ve * 136 + vk];
    f16* vdst1 = &Vs[1][ve * 136 + vk];

    int offKa[4];
    #pragma unroll
    for (int mt = 0; mt < 4; ++mt) {
        const int r = mt * 32 + l5, g = r >> 2;
        offKa[mt] = g * 64 + (((((r & 3) * 2 + hh) + g) & 7) * 8);
    }

    float lsum = 0.f;
    f32x4 O0 = {}, O1 = {};
    f16* Pw = Ps[w];

    f16x8 vv = ld8(vptr);
    gll16(kptr, &Ks[0][w * 512]);
    st8(vdst0, vv);

    for (int kt = 0; kt < 8; ++kt) {
        const int cur = kt & 1;
        if (kt < 7) vv = ld8(vptr + (kt + 1) * 128);
        __syncthreads();
        if (kt < 7) {
            gll16(kptr + (size_t)(kt + 1) * 131072, &Ks[cur ^ 1][w * 512]);
            st8(cur ? vdst0 : vdst1, vv);
        }

        #pragma unroll
        for (int mt = 0; mt < 4; ++mt) {
            f16x8 ka = ld8(&Ks[cur][offKa[mt]]);
            f32x16 Sz = {};
            f32x16 S = MFMA32(ka, qf, Sz);   // S^T[key][q], q = l5

            #pragma unroll
            for (int g = 0; g < 4; ++g) {
                float p0 = EXP2(S[4 * g + 0]);
                float p1 = EXP2(S[4 * g + 1]);
                float p2 = EXP2(S[4 * g + 2]);
                float p3 = EXP2(S[4 * g + 3]);
                lsum += (p0 + p1) + (p2 + p3);
                f16x4 pk;
                pk[0] = (f16)p0; pk[1] = (f16)p1; pk[2] = (f16)p2; pk[3] = (f16)p3;
                st4(&Pw[l5 * 40 + g * 8 + hh * 4], pk);
            }

            f16x8 va  = ld8(&Vs[cur][ll * 136 + mt * 32 + lg * 8]);
            f16x8 pb0 = ld8(&Pw[ll * 40 + lg * 8]);
            f16x8 pb1 = ld8(&Pw[(16 + ll) * 40 + lg * 8]);
            O0 = MFMA16(va, pb0, O0);
            O1 = MFMA16(va, pb1, O1);
        }
    }

    lsum += __shfl_xor(lsum, 32);
    const float i0 = 1.f / __shfl(lsum, ll);
    const float i1 = 1.f / __shfl(lsum, 16 + ll);

    f16x4 o0, o1;
    o0[0]=(f16)(O0[0]*i0); o0[1]=(f16)(O0[1]*i0); o0[2]=(f16)(O0[2]*i0); o0[3]=(f16)(O0[3]*i0);
    o1[0]=(f16)(O1[0]*i1); o1[1]=(f16)(O1[1]*i1); o1[2]=(f16)(O1[2]*i1); o1[3]=(f16)(O1[3]*i1);
    const size_t q0 = rowQ0 + w * 32 + ll;
    st4(merged + q0 * 1024 + colh + lg * 4, o0);
    st4(merged + (q0 + 16) * 1024 + colh + lg * 4, o1);
}

// ---------------- K3: output projection, 64x64, BK=64, dbuf, MFMA32, fp32 out
__global__ __launch_bounds__(256) void o_gemm(
    const f16* __restrict__ A, const f16* __restrict__ Bw,
    const float* __restrict__ bias, float* __restrict__ Cf)
{
    const int bn = blockIdx.x, bm = blockIdx.y;   // grid (16, 32)
    __shared__ f16 As[2 * 4096];
    __shared__ f16 Bs[2 * 4096];
    const int t = threadIdx.x;
    const int w = t >> 6, lane = t & 63, l5 = lane & 31, hh = lane >> 5;
    const int wr = w >> 1, wc = w & 1;            // 2x2 waves cover 64x64
    const int swz = ((lane & 7) ^ (lane >> 3)) * 8;
    const int l7 = l5 & 7;

    const f16* Ap = A  + (size_t)(bm * 64 + w * 8 + (lane >> 3)) * 1024 + swz;
    const f16* Bp = Bw + (size_t)(bn * 64 + w * 8 + (lane >> 3)) * 1024 + swz;

    f32x16 acc = {};

    gll16(Ap,         &As[w * 512]);
    gll16(Ap + 32768, &As[2048 + w * 512]);
    gll16(Bp,         &Bs[w * 512]);
    gll16(Bp + 32768, &Bs[2048 + w * 512]);

    #pragma unroll 2
    for (int kt = 0; kt < 16; ++kt) {
        const int cur = kt & 1;
        __syncthreads();
        if (kt < 15) {
            const f16* Ak = Ap + (kt + 1) * 64;
            const f16* Bk = Bp + (kt + 1) * 64;
            f16* Ad = &As[(cur ^ 1) * 4096 + w * 512];
            f16* Bd = &Bs[(cur ^ 1) * 4096 + w * 512];
            gll16(Ak,         Ad);
            gll16(Ak + 32768, Ad + 2048);
            gll16(Bk,         Bd);
            gll16(Bk + 32768, Bd + 2048);
        }
        const f16* Ac = &As[cur * 4096];
        const f16* Bc = &Bs[cur * 4096];
        #pragma unroll
        for (int ks = 0; ks < 4; ++ks) {
            const int c = ks * 2 + hh;
            f16x8 af = ld8(&Ac[(wr * 32 + l5) * 64 + ((c ^ l7) * 8)]);
            f16x8 bf = ld8(&Bc[(wc * 32 + l5) * 64 + ((c ^ l7) * 8)]);
            acc = MFMA32(af, bf, acc);
        }
    }

    const int n = bn * 64 + wc * 32 + l5;
    const float bv_ = bias[n];
    #pragma unroll
    for (int r = 0; r < 16; ++r) {
        const int m = bm * 64 + wr * 32 + (r & 3) + 8 * (r >> 2) + 4 * hh;
        Cf[(size_t)m * 1024 + n] = acc[r] + bv_;
    }
}

extern "C" void kernel_launch(void* const* d_in, const int* in_sizes, int n_in,
                              void* d_out, int out_size, void* d_ws, size_t ws_size,
                              hipStream_t stream) {
    (void)in_sizes; (void)n_in; (void)out_size; (void)ws_size;
    const float* Q  = (const float*)d_in[0];
    const float* K  = (const float*)d_in[1];
    const float* V  = (const float*)d_in[2];
    const float* Wq = (const float*)d_in[3];
    const float* bq = (const float*)d_in[4];
    const float* Wk = (const float*)d_in[5];
    const float* bk = (const float*)d_in[6];
    const float* Wv = (const float*)d_in[7];
    const float* bv = (const float*)d_in[8];
    const float* Wo = (const float*)d_in[9];
    const float* bo = (const float*)d_in[10];
    float* out = (float*)d_out;

    f16* ws = (f16*)d_ws;
    f16* qlin   = ws + 10485760;
    f16* klin   = ws + 12582912;
    f16* vT     = ws + 14680064;
    f16* merged = ws + 16777216;
    f16* Woc    = ws + 9437184;

    cast_all<<<5120, 256, 0, stream>>>(Q, K, V, Wq, Wk, Wv, Wo, ws);
    qkv_gemm<<<dim3(24, 16), 256, 0, stream>>>(ws, bq, bk, bv, qlin);
    attn<<<dim3(64, 8, 2), 256, 0, stream>>>(qlin, klin, vT, merged);
    o_gemm<<<dim3(16, 32), 256, 0, stream>>>(merged, Woc, bo, out);
}